// Round 8
// baseline (72.826 us; speedup 1.0000x reference)
//
#include <hip/hip_runtime.h>
#include <hip/hip_bf16.h>

typedef __attribute__((ext_vector_type(8))) short bf16x8;
typedef __attribute__((ext_vector_type(8))) unsigned short u16x8;
typedef __attribute__((ext_vector_type(4))) float f32x4;

#define DDIM 1024
#define BM 256
#define BN 128
#define BK 64   // 16 K-steps

__device__ __forceinline__ void gload_lds16(const void* g, void* l) {
  __builtin_amdgcn_global_load_lds((const __attribute__((address_space(1))) void*)g,
                                   (__attribute__((address_space(3))) void*)l,
                                   16, 0, 0);
}

__device__ __forceinline__ unsigned short f2bf(float f) {
  unsigned int u = __float_as_uint(f);
  unsigned int r = (u + 0x7FFFu + ((u >> 16) & 1u)) >> 16;   // RNE
  return (unsigned short)r;
}

// Convert W1/W2/W3 f32 rows -> bf16 rows into workspace (1056 rows).
__global__ __launch_bounds__(256) void s6_convert_w(
    const float* __restrict__ W1, const float* __restrict__ W2,
    const float* __restrict__ W3,
    unsigned short* __restrict__ W1bf, unsigned short* __restrict__ W2bf,
    unsigned short* __restrict__ W3bf)
{
  const int wid = threadIdx.x >> 6, lane = threadIdx.x & 63;
  const int row = blockIdx.x * 4 + wid;
  const float* src;
  unsigned short* dst;
  if (row < 1024)      { src = W1 + (size_t)row * DDIM;          dst = W1bf + (size_t)row * DDIM; }
  else if (row < 1040) { int r = row - 1024; src = W2 + (size_t)r * DDIM; dst = W2bf + (size_t)r * DDIM; }
  else                 { int r = row - 1040; src = W3 + (size_t)r * DDIM; dst = W3bf + (size_t)r * DDIM; }

  const float4* s4 = reinterpret_cast<const float4*>(src + lane * 16);
  unsigned short u[16];
  #pragma unroll
  for (int j = 0; j < 4; ++j) {
    float4 v = s4[j];
    u[j*4+0] = f2bf(v.x); u[j*4+1] = f2bf(v.y);
    u[j*4+2] = f2bf(v.z); u[j*4+3] = f2bf(v.w);
  }
  u16x8* d8 = reinterpret_cast<u16x8*>(dst + lane * 16);
  u16x8 lo, hi;
  #pragma unroll
  for (int j = 0; j < 8; ++j) { lo[j] = u[j]; hi[j] = u[j + 8]; }
  d8[0] = lo; d8[1] = hi;
}

// Fused GEMM + projections + softplus epilogue.
// 8 waves (4M x 2N), 256x128 tile, BK=64, 1 block/CU.
// A staged from f32 X via reg-convert (T14 issue-early / write-late);
// B (W1+W2+W3) staged via gload_lds from pre-converted bf16. 1 barrier/step.
__global__ __launch_bounds__(512, 2) void s6_main_fused(
    const float* __restrict__ X,
    const unsigned short* __restrict__ W1bf,
    const unsigned short* __restrict__ W2bf,
    const unsigned short* __restrict__ W3bf,
    const float* __restrict__ b1,
    const float* __restrict__ b2,
    const float* __restrict__ b3,
    float* __restrict__ Y)
{
  // A: [2][256*64]  B+: [2][192*64] (rows 0-127 W1; 128-143 W2; 144-159 W3; rest pad)
  __shared__ __align__(16) unsigned short lds[2 * 16384 + 2 * 12288];   // 112 KiB
  unsigned short* AB = lds;
  unsigned short* BB = lds + 2 * 16384;

  const int tid  = threadIdx.x;
  const int wid  = tid >> 6;
  const int lane = tid & 63;
  const int tile = (blockIdx.x & 7) * 32 + (blockIdx.x >> 3);   // XCD-chunked
  const int rb   = tile >> 3;
  const int cb   = tile & 7;
  const int row0 = rb * BM;
  const int col0 = cb * BN;
  const int wr = wid >> 1, wc = wid & 1;

  const f32x4 z4 = {0.f, 0.f, 0.f, 0.f};
  f32x4 acc[4][4];
  #pragma unroll
  for (int i = 0; i < 4; ++i)
    #pragma unroll
    for (int j = 0; j < 4; ++j)
      acc[i][j] = z4;
  f32x4 accS[4] = {z4, z4, z4, z4};

  // ---- A reg-staging geometry: thread -> (row = tid>>1, half = tid&1) ----
  const int arow  = tid >> 1;                 // 0..255
  const int ahalf = tid & 1;                  // 32-f32 half of the 64-wide row
  const int arow7 = arow & 7;
  const float* gA = X + (size_t)(row0 + arow) * DDIM + ahalf * 32;

  // ---- B staging (chunk-XOR pre-swizzled source, linear LDS dest) ----
  const int srow = tid >> 3;                  // 0..63
  const int sdch = (lane & 7) ^ (lane >> 3);
  const unsigned short* gbBase = W1bf + (size_t)(col0 + srow) * DDIM + sdch * 8;
  const int sub = srow;
  const unsigned short* gwsrc;
  if (sub < 16)      gwsrc = W2bf + (size_t)sub * DDIM;
  else if (sub < 32) gwsrc = W3bf + (size_t)(sub - 16) * DDIM;
  else               gwsrc = W2bf + (size_t)(sub & 15) * DDIM;   // dummy pad rows
  const unsigned short* gwBase = gwsrc + sdch * 8;

  const int fr = lane & 15;
  const int swz0 = (((lane >> 4) + 0) ^ (fr & 7)) * 8;
  const int swz1 = (((lane >> 4) + 4) ^ (fr & 7)) * 8;

  float4 av[8];

#define ALOAD(KEL) do {                                                        \
    const float* g_ = gA + (KEL);                                              \
    _Pragma("unroll")                                                          \
    for (int j = 0; j < 8; ++j) av[j] = *reinterpret_cast<const float4*>(g_ + j * 4); \
  } while (0)

#define AWRITE(BUF) do {                                                       \
    unsigned short* base_ = AB + (BUF) * 16384 + arow * 64;                    \
    _Pragma("unroll")                                                          \
    for (int c = 0; c < 4; ++c) {                                              \
      u16x8 w_;                                                                \
      float4 lo_ = av[c * 2], hi_ = av[c * 2 + 1];                             \
      w_[0] = f2bf(lo_.x); w_[1] = f2bf(lo_.y); w_[2] = f2bf(lo_.z); w_[3] = f2bf(lo_.w); \
      w_[4] = f2bf(hi_.x); w_[5] = f2bf(hi_.y); w_[6] = f2bf(hi_.z); w_[7] = f2bf(hi_.w); \
      *reinterpret_cast<u16x8*>(base_ + (((ahalf * 4 + c) ^ arow7) * 8)) = w_; \
    }                                                                          \
  } while (0)

#define SB(BUF, KEL, SEG) gload_lds16(gbBase + (KEL) + (SEG) * 64 * DDIM,      \
                                      BB + (BUF) * 12288 + wid * 512 + (SEG) * 4096)
#define SW(BUF, KEL)      gload_lds16(gwBase + (KEL),                          \
                                      BB + (BUF) * 12288 + wid * 512 + 8192)

#define COMPUTE(PAR) do {                                                      \
    const unsigned short* Al = AB + (PAR) * 16384;                             \
    const unsigned short* Bl = BB + (PAR) * 12288;                             \
    bf16x8 af[4][2], bfr[4][2], wfr[2];                                        \
    _Pragma("unroll")                                                          \
    for (int m = 0; m < 4; ++m) {                                              \
      af[m][0] = *reinterpret_cast<const bf16x8*>(&Al[(wr*64 + m*16 + fr)*BK + swz0]); \
      af[m][1] = *reinterpret_cast<const bf16x8*>(&Al[(wr*64 + m*16 + fr)*BK + swz1]); \
    }                                                                          \
    _Pragma("unroll")                                                          \
    for (int n = 0; n < 4; ++n) {                                              \
      bfr[n][0] = *reinterpret_cast<const bf16x8*>(&Bl[(wc*64 + n*16 + fr)*BK + swz0]); \
      bfr[n][1] = *reinterpret_cast<const bf16x8*>(&Bl[(wc*64 + n*16 + fr)*BK + swz1]); \
    }                                                                          \
    wfr[0] = *reinterpret_cast<const bf16x8*>(&Bl[(128 + wc*16 + fr)*BK + swz0]); \
    wfr[1] = *reinterpret_cast<const bf16x8*>(&Bl[(128 + wc*16 + fr)*BK + swz1]); \
    __builtin_amdgcn_s_setprio(1);                                             \
    _Pragma("unroll")                                                          \
    for (int ks = 0; ks < 2; ++ks) {                                           \
      _Pragma("unroll")                                                        \
      for (int m = 0; m < 4; ++m) {                                            \
        _Pragma("unroll")                                                      \
        for (int n = 0; n < 4; ++n)                                            \
          acc[m][n] = __builtin_amdgcn_mfma_f32_16x16x32_bf16(af[m][ks], bfr[n][ks], acc[m][n], 0, 0, 0); \
        accS[m] = __builtin_amdgcn_mfma_f32_16x16x32_bf16(af[m][ks], wfr[ks], accS[m], 0, 0, 0); \
      }                                                                        \
    }                                                                          \
    __builtin_amdgcn_s_setprio(0);                                             \
  } while (0)

  // prologue: stage step 0
  ALOAD(0);
  SB(0, 0, 0); SB(0, 0, 1); SW(0, 0);
  AWRITE(0);                                  // compiler inserts vmcnt for av deps
  __syncthreads();                            // drains gload_lds + ds_write

  for (int t = 0; t < 16; ++t) {
    const int cur = t & 1;
    const int nb  = cur ^ 1;
    const int kn  = (t + 1) * BK;
    if (t < 15) {
      ALOAD(kn);                              // T14: issue early, consume late
      SB(nb, kn, 0); SB(nb, kn, 1); SW(nb, kn);
    }
    __builtin_amdgcn_sched_barrier(0);        // pin load-issue before compute
    COMPUTE(cur);
    if (t < 15) AWRITE(nb);                   // cvt + swizzled ds_write
    __syncthreads();                          // single barrier per step
  }
#undef ALOAD
#undef AWRITE
#undef SB
#undef SW
#undef COMPUTE

  // ---- s[r]: cross-wave exchange (pad 17 = conflict-free) ----
  float* sEx = (float*)lds;           // [2][256][17] f32 = 68 KiB < 112 KiB
  const int n_  = lane & 15;
  const int rgp = (lane >> 4) * 4;
  const float bSelf = (wc == 0 ? b2[n_] : b3[n_]);
  #pragma unroll
  for (int m = 0; m < 4; ++m)
    #pragma unroll
    for (int q = 0; q < 4; ++q)
      sEx[(wc * 256 + wr * 64 + m * 16 + rgp + q) * 17 + n_] = accS[m][q] + bSelf;
  __syncthreads();

  float sv[4][4];
  #pragma unroll
  for (int m = 0; m < 4; ++m) {
    #pragma unroll
    for (int q = 0; q < 4; ++q) {
      const float other = sEx[((wc ^ 1) * 256 + wr * 64 + m * 16 + rgp + q) * 17 + n_];
      float p = (accS[m][q] + bSelf) * other;
      p += __shfl_xor(p, 1, 64);
      p += __shfl_xor(p, 2, 64);
      p += __shfl_xor(p, 4, 64);
      p += __shfl_xor(p, 8, 64);
      sv[m][q] = p;
    }
  }

  // ---- epilogue: x read from f32 input directly ----
  #pragma unroll
  for (int m = 0; m < 4; ++m) {
    #pragma unroll
    for (int q = 0; q < 4; ++q) {
      const int gr = row0 + wr * 64 + m * 16 + rgp + q;
      const float svv = sv[m][q];
      const size_t rbase = (size_t)gr * DDIM;
      #pragma unroll
      for (int n = 0; n < 4; ++n) {
        const int gc = col0 + wc * 64 + n * 16 + fr;
        const float z  = acc[m][n][q] + b1[gc];
        const float sp = fmaxf(z, 0.f) + __logf(1.f + __expf(-fabsf(z)));  // softplus
        const float xv = X[rbase + gc];
        Y[rbase + gc] = xv * svv * sp;
      }
    }
  }
}

extern "C" void kernel_launch(void* const* d_in, const int* in_sizes, int n_in,
                              void* d_out, int out_size, void* d_ws, size_t ws_size,
                              hipStream_t stream) {
  const float* x  = (const float*)d_in[0];
  const float* W1 = (const float*)d_in[1];
  const float* b1 = (const float*)d_in[2];
  const float* W2 = (const float*)d_in[3];
  const float* b2 = (const float*)d_in[4];
  const float* W3 = (const float*)d_in[5];
  const float* b3 = (const float*)d_in[6];
  // d_in[7] = A is provably unused (h is zero-initialized in the reference).

  char* ws = (char*)d_ws;
  unsigned short* W1bf = (unsigned short*)(ws);                 // 2,097,152 B
  unsigned short* W2bf = (unsigned short*)(ws + 2097152);       //    32,768 B
  unsigned short* W3bf = (unsigned short*)(ws + 2097152 + 32768);

  s6_convert_w<<<264, 256, 0, stream>>>(W1, W2, W3, W1bf, W2bf, W3bf);
  s6_main_fused<<<256, 512, 0, stream>>>(x, W1bf, W2bf, W3bf, b1, b2, b3,
                                         (float*)d_out);
}

// Round 12
// 44.646 us; speedup vs baseline: 1.6312x; 1.6312x over previous
//
#include <hip/hip_runtime.h>
#include <hip/hip_bf16.h>

typedef __attribute__((ext_vector_type(8))) short bf16x8;
typedef __attribute__((ext_vector_type(8))) unsigned short u16x8;
typedef __attribute__((ext_vector_type(4))) unsigned short u16x4;
typedef __attribute__((ext_vector_type(4))) float f32x4;

#define DDIM 1024
#define BM 256
#define BN 128
#define BK 64   // 16 K-steps

__device__ __forceinline__ void gload_lds16(const void* g, void* l) {
  __builtin_amdgcn_global_load_lds((const __attribute__((address_space(1))) void*)g,
                                   (__attribute__((address_space(3))) void*)l,
                                   16, 0, 0);
}

__device__ __forceinline__ unsigned short f2bf(float f) {
  unsigned int u = __float_as_uint(f);
  unsigned int r = (u + 0x7FFFu + ((u >> 16) & 1u)) >> 16;   // RNE
  return (unsigned short)r;
}

// Convert f32 -> bf16, fully dense loads AND stores.
// Flat float4 index i: row = i>>8 selects source array; one u16x4 store.
// Row space: [0,8192)=X, [8192,9216)=W1, [9216,9232)=W2, [9232,9248)=W3.
__global__ __launch_bounds__(256) void s6_convert(
    const float* __restrict__ X, const float* __restrict__ W1,
    const float* __restrict__ W2, const float* __restrict__ W3,
    unsigned short* __restrict__ Xbf, unsigned short* __restrict__ W1bf,
    unsigned short* __restrict__ W2bf, unsigned short* __restrict__ W3bf)
{
  const int i   = blockIdx.x * 256 + threadIdx.x;   // float4 index
  const int row = i >> 8;                           // 256 float4 per row
  const int off = (i & 255) * 4;                    // f32 col within row

  const float* src;
  unsigned short* dst;
  if (row < 8192)      { src = X  + (size_t)row * DDIM;        dst = Xbf  + (size_t)row * DDIM; }
  else if (row < 9216) { int r = row - 8192; src = W1 + (size_t)r * DDIM; dst = W1bf + (size_t)r * DDIM; }
  else if (row < 9232) { int r = row - 9216; src = W2 + (size_t)r * DDIM; dst = W2bf + (size_t)r * DDIM; }
  else                 { int r = row - 9232; src = W3 + (size_t)r * DDIM; dst = W3bf + (size_t)r * DDIM; }

  const float4 v = *reinterpret_cast<const float4*>(src + off);
  u16x4 o;
  o[0] = f2bf(v.x); o[1] = f2bf(v.y); o[2] = f2bf(v.z); o[3] = f2bf(v.w);
  *reinterpret_cast<u16x4*>(dst + off) = o;
}

// Fused GEMM + projections + softplus epilogue (R6-proven structure).
// 8 waves (4M x 2N), 256x128 tile, BK=64, 1 block/CU, counted-vmcnt prefetch.
__global__ __launch_bounds__(512, 2) void s6_main_fused(
    const unsigned short* __restrict__ Xbf,
    const unsigned short* __restrict__ W1bf,
    const unsigned short* __restrict__ W2bf,
    const unsigned short* __restrict__ W3bf,
    const float* __restrict__ b1,
    const float* __restrict__ b2,
    const float* __restrict__ b3,
    float* __restrict__ Y)
{
  // A: [2][256*64]  B+: [2][192*64] (rows 0-127 W1; 128-143 W2; 144-159 W3; rest pad)
  __shared__ __align__(16) unsigned short lds[2 * 16384 + 2 * 12288];   // 112 KiB
  unsigned short* AB = lds;
  unsigned short* BB = lds + 2 * 16384;

  const int tid  = threadIdx.x;
  const int wid  = tid >> 6;
  const int lane = tid & 63;
  const int tile = (blockIdx.x & 7) * 32 + (blockIdx.x >> 3);   // XCD-chunked
  const int rb   = tile >> 3;
  const int cb   = tile & 7;
  const int row0 = rb * BM;
  const int col0 = cb * BN;
  const int wr = wid >> 1, wc = wid & 1;

  const f32x4 z4 = {0.f, 0.f, 0.f, 0.f};
  f32x4 acc[4][4];
  #pragma unroll
  for (int i = 0; i < 4; ++i)
    #pragma unroll
    for (int j = 0; j < 4; ++j)
      acc[i][j] = z4;
  f32x4 accS[4] = {z4, z4, z4, z4};   // projection acc (wc=0: W2, wc=1: W3)

  // staging geometry (chunk-XOR pre-swizzled source, linear LDS dest)
  const int srow = tid >> 3;
  const int sdch = (lane & 7) ^ (lane >> 3);
  const unsigned short* gaBase = Xbf  + (size_t)(row0 + srow) * DDIM + sdch * 8;
  const unsigned short* gbBase = W1bf + (size_t)(col0 + srow) * DDIM + sdch * 8;
  const int sub = srow;
  const unsigned short* gwsrc;
  if (sub < 16)      gwsrc = W2bf + (size_t)sub * DDIM;
  else if (sub < 32) gwsrc = W3bf + (size_t)(sub - 16) * DDIM;
  else               gwsrc = W2bf + (size_t)(sub & 15) * DDIM;   // dummy pad rows
  const unsigned short* gwBase = gwsrc + sdch * 8;

  const int fr = lane & 15;
  const int swz0 = (((lane >> 4) + 0) ^ (fr & 7)) * 8;
  const int swz1 = (((lane >> 4) + 4) ^ (fr & 7)) * 8;

#define STAGE(BUF, KEL) do {                                                   \
    const unsigned short* sa_ = gaBase + (KEL);                                \
    const unsigned short* sb_ = gbBase + (KEL);                                \
    unsigned short* la_ = AB + (BUF) * 16384 + wid * 512;                      \
    unsigned short* lb_ = BB + (BUF) * 12288 + wid * 512;                      \
    gload_lds16(sa_,                la_);                                      \
    gload_lds16(sa_ +  64 * DDIM,   la_ + 4096);                               \
    gload_lds16(sa_ + 128 * DDIM,   la_ + 8192);                               \
    gload_lds16(sa_ + 192 * DDIM,   la_ + 12288);                              \
    gload_lds16(sb_,                lb_);                                      \
    gload_lds16(sb_ +  64 * DDIM,   lb_ + 4096);                               \
    gload_lds16(gwBase + (KEL),     lb_ + 8192);                               \
  } while (0)

#define COMPUTE(PAR) do {                                                      \
    const unsigned short* Al = AB + (PAR) * 16384;                             \
    const unsigned short* Bl = BB + (PAR) * 12288;                             \
    bf16x8 af[4][2], bfr[4][2], wfr[2];                                        \
    _Pragma("unroll")                                                          \
    for (int m = 0; m < 4; ++m) {                                              \
      af[m][0] = *reinterpret_cast<const bf16x8*>(&Al[(wr*64 + m*16 + fr)*BK + swz0]); \
      af[m][1] = *reinterpret_cast<const bf16x8*>(&Al[(wr*64 + m*16 + fr)*BK + swz1]); \
    }                                                                          \
    _Pragma("unroll")                                                          \
    for (int n = 0; n < 4; ++n) {                                              \
      bfr[n][0] = *reinterpret_cast<const bf16x8*>(&Bl[(wc*64 + n*16 + fr)*BK + swz0]); \
      bfr[n][1] = *reinterpret_cast<const bf16x8*>(&Bl[(wc*64 + n*16 + fr)*BK + swz1]); \
    }                                                                          \
    wfr[0] = *reinterpret_cast<const bf16x8*>(&Bl[(128 + wc*16 + fr)*BK + swz0]); \
    wfr[1] = *reinterpret_cast<const bf16x8*>(&Bl[(128 + wc*16 + fr)*BK + swz1]); \
    __builtin_amdgcn_s_setprio(1);                                             \
    _Pragma("unroll")                                                          \
    for (int ks = 0; ks < 2; ++ks) {                                           \
      _Pragma("unroll")                                                        \
      for (int m = 0; m < 4; ++m) {                                            \
        _Pragma("unroll")                                                      \
        for (int n = 0; n < 4; ++n)                                            \
          acc[m][n] = __builtin_amdgcn_mfma_f32_16x16x32_bf16(af[m][ks], bfr[n][ks], acc[m][n], 0, 0, 0); \
        accS[m] = __builtin_amdgcn_mfma_f32_16x16x32_bf16(af[m][ks], wfr[ks], accS[m], 0, 0, 0); \
      }                                                                        \
    }                                                                          \
    __builtin_amdgcn_s_setprio(0);                                             \
  } while (0)

#define STEP(J, PAR) do {                                                      \
    if ((J) < 15) {                                                            \
      STAGE((PAR) ^ 1, ((J) + 1) * BK);                                        \
      asm volatile("s_waitcnt vmcnt(7)" ::: "memory");                         \
    } else {                                                                   \
      asm volatile("s_waitcnt vmcnt(0)" ::: "memory");                         \
    }                                                                          \
    __builtin_amdgcn_s_barrier();                                              \
    __builtin_amdgcn_sched_barrier(0);                                         \
    COMPUTE(PAR);                                                              \
    __builtin_amdgcn_s_barrier();                                              \
  } while (0)

  STAGE(0, 0);
  asm volatile("s_waitcnt vmcnt(0)" ::: "memory");
  __builtin_amdgcn_s_barrier();

  for (int jj = 0; jj < 16; jj += 2) {
    STEP(jj, 0);
    STEP(jj + 1, 1);
  }
#undef STEP
#undef COMPUTE
#undef STAGE

  // ---- s[r]: cross-wave exchange of the two projections (pad 17 = conflict-free) ----
  float* sEx = (float*)lds;           // [2][256][17] f32 = 68 KiB < 112 KiB
  const int n_  = lane & 15;
  const int rgp = (lane >> 4) * 4;
  const float bSelf = (wc == 0 ? b2[n_] : b3[n_]);
  #pragma unroll
  for (int m = 0; m < 4; ++m)
    #pragma unroll
    for (int q = 0; q < 4; ++q)
      sEx[(wc * 256 + wr * 64 + m * 16 + rgp + q) * 17 + n_] = accS[m][q] + bSelf;
  __syncthreads();

  float sv[4][4];
  #pragma unroll
  for (int m = 0; m < 4; ++m) {
    #pragma unroll
    for (int q = 0; q < 4; ++q) {
      const float other = sEx[((wc ^ 1) * 256 + wr * 64 + m * 16 + rgp + q) * 17 + n_];
      float p = (accS[m][q] + bSelf) * other;
      p += __shfl_xor(p, 1, 64);
      p += __shfl_xor(p, 2, 64);
      p += __shfl_xor(p, 4, 64);
      p += __shfl_xor(p, 8, 64);
      sv[m][q] = p;
    }
  }

  // ---- epilogue: D mapping col=lane&15, row=(lane>>4)*4+reg ----
  #pragma unroll
  for (int m = 0; m < 4; ++m) {
    #pragma unroll
    for (int q = 0; q < 4; ++q) {
      const int gr = row0 + wr * 64 + m * 16 + rgp + q;
      const float svv = sv[m][q];
      const size_t rbase = (size_t)gr * DDIM;
      #pragma unroll
      for (int n = 0; n < 4; ++n) {
        const int gc = col0 + wc * 64 + n * 16 + fr;
        const float z  = acc[m][n][q] + b1[gc];
        // softplus via hw exp2/log2 (v_exp_f32 / v_log_f32)
        const float e  = exp2f(-1.44269504f * fabsf(z));
        const float sp = fmaxf(z, 0.f) + 0.69314718f * log2f(1.f + e);
        const float xv = __bfloat162float(*(const __hip_bfloat16*)&Xbf[rbase + gc]);
        Y[rbase + gc] = xv * svv * sp;
      }
    }
  }
}

extern "C" void kernel_launch(void* const* d_in, const int* in_sizes, int n_in,
                              void* d_out, int out_size, void* d_ws, size_t ws_size,
                              hipStream_t stream) {
  const float* x  = (const float*)d_in[0];
  const float* W1 = (const float*)d_in[1];
  const float* b1 = (const float*)d_in[2];
  const float* W2 = (const float*)d_in[3];
  const float* b2 = (const float*)d_in[4];
  const float* W3 = (const float*)d_in[5];
  const float* b3 = (const float*)d_in[6];
  // d_in[7] = A is provably unused (h is zero-initialized in the reference).

  char* ws = (char*)d_ws;
  unsigned short* Xbf  = (unsigned short*)(ws);                          // 16,777,216 B
  unsigned short* W1bf = (unsigned short*)(ws + 16777216);               //  2,097,152 B
  unsigned short* W2bf = (unsigned short*)(ws + 16777216 + 2097152);     //     32,768 B
  unsigned short* W3bf = (unsigned short*)(ws + 16777216 + 2097152 + 32768);

  // 9248 rows * 256 float4/row = 2,367,488 float4 = 9248 blocks * 256 threads
  s6_convert<<<9248, 256, 0, stream>>>(x, W1, W2, W3, Xbf, W1bf, W2bf, W3bf);
  s6_main_fused<<<256, 512, 0, stream>>>(Xbf, W1bf, W2bf, W3bf, b1, b2, b3,
                                         (float*)d_out);
}

// Round 13
// 43.609 us; speedup vs baseline: 1.6700x; 1.0238x over previous
//
#include <hip/hip_runtime.h>
#include <hip/hip_bf16.h>

typedef __attribute__((ext_vector_type(8))) short bf16x8;
typedef __attribute__((ext_vector_type(8))) unsigned short u16x8;
typedef __attribute__((ext_vector_type(4))) unsigned short u16x4;
typedef __attribute__((ext_vector_type(4))) float f32x4;

#define DDIM 1024
#define BM 128
#define BN 128
#define BK 64   // 16 K-steps

__device__ __forceinline__ void gload_lds16(const void* g, void* l) {
  __builtin_amdgcn_global_load_lds((const __attribute__((address_space(1))) void*)g,
                                   (__attribute__((address_space(3))) void*)l,
                                   16, 0, 0);
}

__device__ __forceinline__ unsigned short f2bf(float f) {
  unsigned int u = __float_as_uint(f);
  unsigned int r = (u + 0x7FFFu + ((u >> 16) & 1u)) >> 16;   // RNE
  return (unsigned short)r;
}

// Convert f32 -> bf16, dense loads and stores (R12-proven).
__global__ __launch_bounds__(256) void s6_convert(
    const float* __restrict__ X, const float* __restrict__ W1,
    const float* __restrict__ W2, const float* __restrict__ W3,
    unsigned short* __restrict__ Xbf, unsigned short* __restrict__ W1bf,
    unsigned short* __restrict__ W2bf, unsigned short* __restrict__ W3bf)
{
  const int i   = blockIdx.x * 256 + threadIdx.x;   // float4 index
  const int row = i >> 8;
  const int off = (i & 255) * 4;

  const float* src;
  unsigned short* dst;
  if (row < 8192)      { src = X  + (size_t)row * DDIM;        dst = Xbf  + (size_t)row * DDIM; }
  else if (row < 9216) { int r = row - 8192; src = W1 + (size_t)r * DDIM; dst = W1bf + (size_t)r * DDIM; }
  else if (row < 9232) { int r = row - 9216; src = W2 + (size_t)r * DDIM; dst = W2bf + (size_t)r * DDIM; }
  else                 { int r = row - 9232; src = W3 + (size_t)r * DDIM; dst = W3bf + (size_t)r * DDIM; }

  const float4 v = *reinterpret_cast<const float4*>(src + off);
  u16x4 o;
  o[0] = f2bf(v.x); o[1] = f2bf(v.y); o[2] = f2bf(v.z); o[3] = f2bf(v.w);
  *reinterpret_cast<u16x4*>(dst + off) = o;
}

// Fused GEMM + projections + softplus epilogue.
// 128x128 tile, 8 waves (4M x 2N, wave-tile 32x64), BK=64, LDS 72KB ->
// 2 blocks/CU (16 waves/CU): cross-block overlap hides epilogue + barriers.
__global__ __launch_bounds__(512, 4) void s6_main_fused(
    const unsigned short* __restrict__ Xbf,
    const unsigned short* __restrict__ W1bf,
    const unsigned short* __restrict__ W2bf,
    const unsigned short* __restrict__ W3bf,
    const float* __restrict__ b1,
    const float* __restrict__ b2,
    const float* __restrict__ b3,
    float* __restrict__ Y)
{
  // A: [2][128*64]  B+: [2][192*64] (rows 0-127 W1 cols; 128-143 W2; 144-159 W3; rest pad)
  __shared__ __align__(16) unsigned short lds[2 * 8192 + 2 * 12288];   // 80 KiB... A 32KB + B 48KB = 72KiB... wait: 2*8192*2B=32KB, 2*12288*2B=48KB -> 80KB total? No: elements: 2*8192 + 2*12288 = 40960 elems * 2B = 80KB. Hmm—see note below: B padded rows trimmed to 160.
  unsigned short* AB = lds;                    // [2][8192]  (128x64)
  unsigned short* BB = lds + 2 * 8192;         // [2][12288] (192x64)

  const int tid  = threadIdx.x;
  const int wid  = tid >> 6;
  const int lane = tid & 63;
  // XCD-chunked: 512 tiles; XCD x owns 64 consecutive = 8 row-panels x 8 cols.
  const int tile = (blockIdx.x & 7) * 64 + (blockIdx.x >> 3);
  const int rb   = tile >> 3;          // 64 row-blocks
  const int cb   = tile & 7;           // 8 col-blocks
  const int row0 = rb * BM;
  const int col0 = cb * BN;
  const int wr = wid >> 1, wc = wid & 1;   // 4M x 2N, wave-tile 32x64

  const f32x4 z4 = {0.f, 0.f, 0.f, 0.f};
  f32x4 acc[2][4];
  #pragma unroll
  for (int i = 0; i < 2; ++i)
    #pragma unroll
    for (int j = 0; j < 4; ++j)
      acc[i][j] = z4;
  f32x4 accS[2] = {z4, z4};            // projection acc (wc=0: W2, wc=1: W3)

  // staging geometry (chunk-XOR pre-swizzled source, linear LDS dest)
  // slot s = round*512 + tid -> row = round*64 + (tid>>3), slot chunk = tid&7;
  // slot holds data chunk (tid&7) ^ ((tid>>3)&7).
  const int srow = tid >> 3;                    // 0..63 (+round*64)
  const int sdch = (lane & 7) ^ (lane >> 3);
  const unsigned short* gaBase = Xbf  + (size_t)(row0 + srow) * DDIM + sdch * 8;
  const unsigned short* gbBase = W1bf + (size_t)(col0 + srow) * DDIM + sdch * 8;
  // B round 2 (rows 128-191): sub<16 -> W2; sub<32 -> W3; else pad (W2 dup).
  const int sub = srow;
  const unsigned short* gwsrc;
  if (sub < 16)      gwsrc = W2bf + (size_t)sub * DDIM;
  else if (sub < 32) gwsrc = W3bf + (size_t)(sub - 16) * DDIM;
  else               gwsrc = W2bf + (size_t)(sub & 15) * DDIM;
  const unsigned short* gwBase = gwsrc + sdch * 8;

  const int fr = lane & 15;
  const int swz0 = (((lane >> 4) + 0) ^ (fr & 7)) * 8;
  const int swz1 = (((lane >> 4) + 4) ^ (fr & 7)) * 8;

#define STAGE(BUF, KEL) do {                                                   \
    const unsigned short* sa_ = gaBase + (KEL);                                \
    const unsigned short* sb_ = gbBase + (KEL);                                \
    unsigned short* la_ = AB + (BUF) * 8192  + wid * 512;                      \
    unsigned short* lb_ = BB + (BUF) * 12288 + wid * 512;                      \
    gload_lds16(sa_,              la_);                                        \
    gload_lds16(sa_ + 64 * DDIM,  la_ + 4096);                                 \
    gload_lds16(sb_,              lb_);                                        \
    gload_lds16(sb_ + 64 * DDIM,  lb_ + 4096);                                 \
    gload_lds16(gwBase + (KEL),   lb_ + 8192);                                 \
  } while (0)

#define COMPUTE(PAR) do {                                                      \
    const unsigned short* Al = AB + (PAR) * 8192;                              \
    const unsigned short* Bl = BB + (PAR) * 12288;                             \
    _Pragma("unroll")                                                          \
    for (int ks = 0; ks < 2; ++ks) {                                           \
      const int swz = ks ? swz1 : swz0;                                        \
      bf16x8 a0 = *reinterpret_cast<const bf16x8*>(&Al[(wr*32 +  0 + fr)*BK + swz]); \
      bf16x8 a1 = *reinterpret_cast<const bf16x8*>(&Al[(wr*32 + 16 + fr)*BK + swz]); \
      bf16x8 g0 = *reinterpret_cast<const bf16x8*>(&Bl[(wc*64 +  0 + fr)*BK + swz]); \
      bf16x8 g1 = *reinterpret_cast<const bf16x8*>(&Bl[(wc*64 + 16 + fr)*BK + swz]); \
      bf16x8 g2 = *reinterpret_cast<const bf16x8*>(&Bl[(wc*64 + 32 + fr)*BK + swz]); \
      bf16x8 g3 = *reinterpret_cast<const bf16x8*>(&Bl[(wc*64 + 48 + fr)*BK + swz]); \
      bf16x8 wf = *reinterpret_cast<const bf16x8*>(&Bl[(128 + wc*16 + fr)*BK + swz]); \
      __builtin_amdgcn_s_setprio(1);                                           \
      acc[0][0] = __builtin_amdgcn_mfma_f32_16x16x32_bf16(a0, g0, acc[0][0], 0, 0, 0); \
      acc[0][1] = __builtin_amdgcn_mfma_f32_16x16x32_bf16(a0, g1, acc[0][1], 0, 0, 0); \
      acc[0][2] = __builtin_amdgcn_mfma_f32_16x16x32_bf16(a0, g2, acc[0][2], 0, 0, 0); \
      acc[0][3] = __builtin_amdgcn_mfma_f32_16x16x32_bf16(a0, g3, acc[0][3], 0, 0, 0); \
      acc[1][0] = __builtin_amdgcn_mfma_f32_16x16x32_bf16(a1, g0, acc[1][0], 0, 0, 0); \
      acc[1][1] = __builtin_amdgcn_mfma_f32_16x16x32_bf16(a1, g1, acc[1][1], 0, 0, 0); \
      acc[1][2] = __builtin_amdgcn_mfma_f32_16x16x32_bf16(a1, g2, acc[1][2], 0, 0, 0); \
      acc[1][3] = __builtin_amdgcn_mfma_f32_16x16x32_bf16(a1, g3, acc[1][3], 0, 0, 0); \
      accS[0]   = __builtin_amdgcn_mfma_f32_16x16x32_bf16(a0, wf, accS[0], 0, 0, 0); \
      accS[1]   = __builtin_amdgcn_mfma_f32_16x16x32_bf16(a1, wf, accS[1], 0, 0, 0); \
      __builtin_amdgcn_s_setprio(0);                                           \
    }                                                                          \
  } while (0)

#define STEP(J, PAR) do {                                                      \
    if ((J) < 15) {                                                            \
      STAGE((PAR) ^ 1, ((J) + 1) * BK);                                        \
      asm volatile("s_waitcnt vmcnt(5)" ::: "memory");                         \
    } else {                                                                   \
      asm volatile("s_waitcnt vmcnt(0)" ::: "memory");                         \
    }                                                                          \
    __builtin_amdgcn_s_barrier();                                              \
    __builtin_amdgcn_sched_barrier(0);                                         \
    COMPUTE(PAR);                                                              \
    __builtin_amdgcn_s_barrier();                                              \
  } while (0)

  STAGE(0, 0);
  asm volatile("s_waitcnt vmcnt(0)" ::: "memory");
  __builtin_amdgcn_s_barrier();

  for (int jj = 0; jj < 16; jj += 2) {
    STEP(jj, 0);
    STEP(jj + 1, 1);
  }
#undef STEP
#undef COMPUTE
#undef STAGE

  // ---- s[r]: cross-wave exchange of the two projections (pad 17 = conflict-free) ----
  float* sEx = (float*)lds;            // [2][128][17] f32 = 17.4 KiB < 80 KiB
  const int n_  = lane & 15;
  const int rgp = (lane >> 4) * 4;
  const float bSelf = (wc == 0 ? b2[n_] : b3[n_]);
  #pragma unroll
  for (int m = 0; m < 2; ++m)
    #pragma unroll
    for (int q = 0; q < 4; ++q)
      sEx[(wc * 128 + wr * 32 + m * 16 + rgp + q) * 17 + n_] = accS[m][q] + bSelf;
  __syncthreads();

  float sv[2][4];
  #pragma unroll
  for (int m = 0; m < 2; ++m) {
    #pragma unroll
    for (int q = 0; q < 4; ++q) {
      const float other = sEx[((wc ^ 1) * 128 + wr * 32 + m * 16 + rgp + q) * 17 + n_];
      float p = (accS[m][q] + bSelf) * other;
      p += __shfl_xor(p, 1, 64);
      p += __shfl_xor(p, 2, 64);
      p += __shfl_xor(p, 4, 64);
      p += __shfl_xor(p, 8, 64);
      sv[m][q] = p;
    }
  }

  // ---- epilogue: D mapping col=lane&15, row=(lane>>4)*4+reg ----
  #pragma unroll
  for (int m = 0; m < 2; ++m) {
    #pragma unroll
    for (int q = 0; q < 4; ++q) {
      const int gr = row0 + wr * 32 + m * 16 + rgp + q;
      const float svv = sv[m][q];
      const size_t rbase = (size_t)gr * DDIM;
      #pragma unroll
      for (int n = 0; n < 4; ++n) {
        const int gc = col0 + wc * 64 + n * 16 + fr;
        const float z  = acc[m][n][q] + b1[gc];
        const float e  = exp2f(-1.44269504f * fabsf(z));
        const float sp = fmaxf(z, 0.f) + 0.69314718f * log2f(1.f + e);
        const float xv = __bfloat162float(*(const __hip_bfloat16*)&Xbf[rbase + gc]);
        Y[rbase + gc] = xv * svv * sp;
      }
    }
  }
}

extern "C" void kernel_launch(void* const* d_in, const int* in_sizes, int n_in,
                              void* d_out, int out_size, void* d_ws, size_t ws_size,
                              hipStream_t stream) {
  const float* x  = (const float*)d_in[0];
  const float* W1 = (const float*)d_in[1];
  const float* b1 = (const float*)d_in[2];
  const float* W2 = (const float*)d_in[3];
  const float* b2 = (const float*)d_in[4];
  const float* W3 = (const float*)d_in[5];
  const float* b3 = (const float*)d_in[6];
  // d_in[7] = A is provably unused (h is zero-initialized in the reference).

  char* ws = (char*)d_ws;
  unsigned short* Xbf  = (unsigned short*)(ws);                          // 16,777,216 B
  unsigned short* W1bf = (unsigned short*)(ws + 16777216);               //  2,097,152 B
  unsigned short* W2bf = (unsigned short*)(ws + 16777216 + 2097152);     //     32,768 B
  unsigned short* W3bf = (unsigned short*)(ws + 16777216 + 2097152 + 32768);

  s6_convert<<<9248, 256, 0, stream>>>(x, W1, W2, W3, Xbf, W1bf, W2bf, W3bf);
  s6_main_fused<<<512, 512, 0, stream>>>(Xbf, W1bf, W2bf, W3bf, b1, b2, b3,
                                         (float*)d_out);
}

// Round 14
// 43.111 us; speedup vs baseline: 1.6893x; 1.0115x over previous
//
#include <hip/hip_runtime.h>
#include <hip/hip_bf16.h>

typedef __attribute__((ext_vector_type(8))) short bf16x8;
typedef __attribute__((ext_vector_type(4))) unsigned short u16x4;
typedef __attribute__((ext_vector_type(4))) float f32x4;

#define DDIM 1024
#define BM 128
#define BN 128
#define BK 64   // 16 K-steps

__device__ __forceinline__ void gload_lds16(const void* g, void* l) {
  __builtin_amdgcn_global_load_lds((const __attribute__((address_space(1))) void*)g,
                                   (__attribute__((address_space(3))) void*)l,
                                   16, 0, 0);
}

__device__ __forceinline__ unsigned short f2bf(float f) {
  unsigned int u = __float_as_uint(f);
  unsigned int r = (u + 0x7FFFu + ((u >> 16) & 1u)) >> 16;   // RNE
  return (unsigned short)r;
}

// Convert W1/W2/W3 f32 -> bf16 (1056 rows only; X stays f32).
__global__ __launch_bounds__(256) void s6_convert_w(
    const float* __restrict__ W1, const float* __restrict__ W2,
    const float* __restrict__ W3,
    unsigned short* __restrict__ W1bf, unsigned short* __restrict__ W2bf,
    unsigned short* __restrict__ W3bf)
{
  const int i   = blockIdx.x * 256 + threadIdx.x;   // float4 index
  const int row = i >> 8;
  const int off = (i & 255) * 4;

  const float* src;
  unsigned short* dst;
  if (row < 1024)      { src = W1 + (size_t)row * DDIM;          dst = W1bf + (size_t)row * DDIM; }
  else if (row < 1040) { int r = row - 1024; src = W2 + (size_t)r * DDIM; dst = W2bf + (size_t)r * DDIM; }
  else                 { int r = row - 1040; src = W3 + (size_t)r * DDIM; dst = W3bf + (size_t)r * DDIM; }

  const float4 v = *reinterpret_cast<const float4*>(src + off);
  u16x4 o;
  o[0] = f2bf(v.x); o[1] = f2bf(v.y); o[2] = f2bf(v.z); o[3] = f2bf(v.w);
  *reinterpret_cast<u16x4*>(dst + off) = o;
}

// Fused GEMM + projections + softplus epilogue.
// 128x128 tile, 8 waves, BK=64, 2 blocks/CU.
// A staged from f32 X: coalesced reg-load (issue-early) + cvt_pk + swizzled
// ds_write_b64 (write-late, T14). B (W1/W2/W3 bf16) via gload_lds.
__global__ __launch_bounds__(512, 4) void s6_main_fused(
    const float* __restrict__ X,
    const unsigned short* __restrict__ W1bf,
    const unsigned short* __restrict__ W2bf,
    const unsigned short* __restrict__ W3bf,
    const float* __restrict__ b1,
    const float* __restrict__ b2,
    const float* __restrict__ b3,
    float* __restrict__ Y)
{
  // A: [2][8192] (128x64 bf16)  B+: [2][12288] (192x64; 0-127 W1; 128-143 W2; 144-159 W3)
  __shared__ __align__(16) unsigned short lds[2 * 8192 + 2 * 12288];   // 80 KiB
  unsigned short* AB = lds;
  unsigned short* BB = lds + 2 * 8192;

  const int tid  = threadIdx.x;
  const int wid  = tid >> 6;
  const int lane = tid & 63;
  const int tile = (blockIdx.x & 7) * 64 + (blockIdx.x >> 3);   // XCD-chunked
  const int rb   = tile >> 3;
  const int cb   = tile & 7;
  const int row0 = rb * BM;
  const int col0 = cb * BN;
  const int wr = wid >> 1, wc = wid & 1;   // 4M x 2N, wave-tile 32x64

  const f32x4 z4 = {0.f, 0.f, 0.f, 0.f};
  f32x4 acc[2][4];
  #pragma unroll
  for (int i = 0; i < 2; ++i)
    #pragma unroll
    for (int j = 0; j < 4; ++j)
      acc[i][j] = z4;
  f32x4 accS[2] = {z4, z4};            // projection acc (wc=0: W2, wc=1: W3)

  // ---- A reg-staging: 16 threads/row slice, 256B contiguous segments ----
  const int arow  = tid >> 4;          // 0..31 (+ j*32)
  const int acol  = (tid & 15) * 4;    // f32 col within 64-wide K-slice
  const int ac8   = (tid & 15) >> 1;   // 8-elem chunk index
  const int ahalf = (tid & 1) * 4;     // elem offset within chunk
  const float* gA = X + (size_t)(row0 + arow) * DDIM + acol;

  // ---- B staging (chunk-XOR pre-swizzled source, linear LDS dest) ----
  const int srow = tid >> 3;           // 0..63
  const int sdch = (lane & 7) ^ (lane >> 3);
  const unsigned short* gbBase = W1bf + (size_t)(col0 + srow) * DDIM + sdch * 8;
  const unsigned short* gwsrc;
  if (srow < 16)      gwsrc = W2bf + (size_t)srow * DDIM;
  else if (srow < 32) gwsrc = W3bf + (size_t)(srow - 16) * DDIM;
  else                gwsrc = W2bf + (size_t)(srow & 15) * DDIM;   // pad rows
  const unsigned short* gwBase = gwsrc + sdch * 8;

  const int fr = lane & 15;
  const int swz0 = (((lane >> 4) + 0) ^ (fr & 7)) * 8;
  const int swz1 = (((lane >> 4) + 4) ^ (fr & 7)) * 8;

  float4 av[4];

#define ALOAD(KEL) do {                                                        \
    _Pragma("unroll")                                                          \
    for (int j = 0; j < 4; ++j)                                                \
      av[j] = *reinterpret_cast<const float4*>(gA + (size_t)(j * 32) * DDIM + (KEL)); \
  } while (0)

#define AWRITE(BUF) do {                                                       \
    _Pragma("unroll")                                                          \
    for (int j = 0; j < 4; ++j) {                                              \
      const int row_ = arow + j * 32;                                          \
      const int off_ = row_ * 64 + ((ac8 ^ (row_ & 7)) << 3) + ahalf;          \
      uint2 w_;                                                                \
      asm("v_cvt_pk_bf16_f32 %0, %1, %2" : "=v"(w_.x) : "v"(av[j].x), "v"(av[j].y)); \
      asm("v_cvt_pk_bf16_f32 %0, %1, %2" : "=v"(w_.y) : "v"(av[j].z), "v"(av[j].w)); \
      *reinterpret_cast<uint2*>(AB + (BUF) * 8192 + off_) = w_;                \
    }                                                                          \
  } while (0)

#define SBW(BUF, KEL) do {                                                     \
    const unsigned short* sb_ = gbBase + (KEL);                                \
    unsigned short* lb_ = BB + (BUF) * 12288 + wid * 512;                      \
    gload_lds16(sb_,              lb_);                                        \
    gload_lds16(sb_ + 64 * DDIM,  lb_ + 4096);                                 \
    gload_lds16(gwBase + (KEL),   lb_ + 8192);                                 \
  } while (0)

#define COMPUTE(PAR) do {                                                      \
    const unsigned short* Al = AB + (PAR) * 8192;                              \
    const unsigned short* Bl = BB + (PAR) * 12288;                             \
    _Pragma("unroll")                                                          \
    for (int ks = 0; ks < 2; ++ks) {                                           \
      const int swz = ks ? swz1 : swz0;                                        \
      bf16x8 a0 = *reinterpret_cast<const bf16x8*>(&Al[(wr*32 +  0 + fr)*BK + swz]); \
      bf16x8 a1 = *reinterpret_cast<const bf16x8*>(&Al[(wr*32 + 16 + fr)*BK + swz]); \
      bf16x8 g0 = *reinterpret_cast<const bf16x8*>(&Bl[(wc*64 +  0 + fr)*BK + swz]); \
      bf16x8 g1 = *reinterpret_cast<const bf16x8*>(&Bl[(wc*64 + 16 + fr)*BK + swz]); \
      bf16x8 g2 = *reinterpret_cast<const bf16x8*>(&Bl[(wc*64 + 32 + fr)*BK + swz]); \
      bf16x8 g3 = *reinterpret_cast<const bf16x8*>(&Bl[(wc*64 + 48 + fr)*BK + swz]); \
      bf16x8 wf = *reinterpret_cast<const bf16x8*>(&Bl[(128 + wc*16 + fr)*BK + swz]); \
      __builtin_amdgcn_s_setprio(1);                                           \
      acc[0][0] = __builtin_amdgcn_mfma_f32_16x16x32_bf16(a0, g0, acc[0][0], 0, 0, 0); \
      acc[0][1] = __builtin_amdgcn_mfma_f32_16x16x32_bf16(a0, g1, acc[0][1], 0, 0, 0); \
      acc[0][2] = __builtin_amdgcn_mfma_f32_16x16x32_bf16(a0, g2, acc[0][2], 0, 0, 0); \
      acc[0][3] = __builtin_amdgcn_mfma_f32_16x16x32_bf16(a0, g3, acc[0][3], 0, 0, 0); \
      acc[1][0] = __builtin_amdgcn_mfma_f32_16x16x32_bf16(a1, g0, acc[1][0], 0, 0, 0); \
      acc[1][1] = __builtin_amdgcn_mfma_f32_16x16x32_bf16(a1, g1, acc[1][1], 0, 0, 0); \
      acc[1][2] = __builtin_amdgcn_mfma_f32_16x16x32_bf16(a1, g2, acc[1][2], 0, 0, 0); \
      acc[1][3] = __builtin_amdgcn_mfma_f32_16x16x32_bf16(a1, g3, acc[1][3], 0, 0, 0); \
      accS[0]   = __builtin_amdgcn_mfma_f32_16x16x32_bf16(a0, wf, accS[0], 0, 0, 0); \
      accS[1]   = __builtin_amdgcn_mfma_f32_16x16x32_bf16(a1, wf, accS[1], 0, 0, 0); \
      __builtin_amdgcn_s_setprio(0);                                           \
    }                                                                          \
  } while (0)

  // prologue: tile 0
  ALOAD(0);
  SBW(0, 0);
  asm volatile("s_waitcnt vmcnt(3)" ::: "memory");   // A-loads landed (3 SBW in flight)
  AWRITE(0);
  __syncthreads();                                   // drains SBW vmcnt + AWRITE lgkm

  for (int t = 0; t < 16; ++t) {
    const int cur = t & 1;
    const int nb  = cur ^ 1;
    const int kn  = (t + 1) * BK;
    if (t < 15) {
      ALOAD(kn);                    // issue-early: 4 f32x4 loads for next tile
      SBW(nb, kn);                  // 3 gload_lds for next tile's B
    }
    __builtin_amdgcn_sched_barrier(0);
    COMPUTE(cur);
    if (t < 15) {
      asm volatile("s_waitcnt vmcnt(3)" ::: "memory");  // retire the 4 A-loads
      AWRITE(nb);                   // cvt_pk + swizzled ds_write_b64 (write-late)
    }
    __syncthreads();                // B landed + A writes visible -> next step
  }
#undef ALOAD
#undef AWRITE
#undef SBW
#undef COMPUTE

  // ---- s[r]: cross-wave exchange of the two projections (pad 17 = conflict-free) ----
  float* sEx = (float*)lds;            // [2][128][17] f32 = 17.4 KiB
  const int n_  = lane & 15;
  const int rgp = (lane >> 4) * 4;
  const float bSelf = (wc == 0 ? b2[n_] : b3[n_]);
  #pragma unroll
  for (int m = 0; m < 2; ++m)
    #pragma unroll
    for (int q = 0; q < 4; ++q)
      sEx[(wc * 128 + wr * 32 + m * 16 + rgp + q) * 17 + n_] = accS[m][q] + bSelf;
  __syncthreads();

  float sv[2][4];
  #pragma unroll
  for (int m = 0; m < 2; ++m) {
    #pragma unroll
    for (int q = 0; q < 4; ++q) {
      const float other = sEx[((wc ^ 1) * 128 + wr * 32 + m * 16 + rgp + q) * 17 + n_];
      float p = (accS[m][q] + bSelf) * other;
      p += __shfl_xor(p, 1, 64);
      p += __shfl_xor(p, 2, 64);
      p += __shfl_xor(p, 4, 64);
      p += __shfl_xor(p, 8, 64);
      sv[m][q] = p;
    }
  }

  // ---- epilogue: x read from f32 input (L2/L3-hot) ----
  #pragma unroll
  for (int m = 0; m < 2; ++m) {
    #pragma unroll
    for (int q = 0; q < 4; ++q) {
      const int gr = row0 + wr * 32 + m * 16 + rgp + q;
      const float svv = sv[m][q];
      const size_t rbase = (size_t)gr * DDIM;
      #pragma unroll
      for (int n = 0; n < 4; ++n) {
        const int gc = col0 + wc * 64 + n * 16 + fr;
        const float z  = acc[m][n][q] + b1[gc];
        const float e  = exp2f(-1.44269504f * fabsf(z));
        const float sp = fmaxf(z, 0.f) + 0.69314718f * log2f(1.f + e);
        const float xv = X[rbase + gc];
        Y[rbase + gc] = xv * svv * sp;
      }
    }
  }
}

extern "C" void kernel_launch(void* const* d_in, const int* in_sizes, int n_in,
                              void* d_out, int out_size, void* d_ws, size_t ws_size,
                              hipStream_t stream) {
  const float* x  = (const float*)d_in[0];
  const float* W1 = (const float*)d_in[1];
  const float* b1 = (const float*)d_in[2];
  const float* W2 = (const float*)d_in[3];
  const float* b2 = (const float*)d_in[4];
  const float* W3 = (const float*)d_in[5];
  const float* b3 = (const float*)d_in[6];
  // d_in[7] = A is provably unused (h is zero-initialized in the reference).

  char* ws = (char*)d_ws;
  unsigned short* W1bf = (unsigned short*)(ws);                 // 2,097,152 B
  unsigned short* W2bf = (unsigned short*)(ws + 2097152);       //    32,768 B
  unsigned short* W3bf = (unsigned short*)(ws + 2097152 + 32768);

  // 1056 rows * 256 float4/row = 270,336 float4 -> 1056 blocks * 256 threads
  s6_convert_w<<<1056, 256, 0, stream>>>(W1, W2, W3, W1bf, W2bf, W3bf);
  s6_main_fused<<<512, 512, 0, stream>>>(x, W1bf, W2bf, W3bf, b1, b2, b3,
                                         (float*)d_out);
}